// Round 1
// 550.008 us; speedup vs baseline: 1.0975x; 1.0975x over previous
//
#include <hip/hip_runtime.h>
#include <hip/hip_bf16.h>

#define B_ 4
#define S_ 4096
#define E_ 1024
#define H_ 16
#define D_ 64
#define NS_ 1024
#define M_ (B_*S_)
#define K_ E_
#define DELTA 0.12f
#define BANDCAP 96

typedef __attribute__((ext_vector_type(8))) short bf16x8;
typedef __attribute__((ext_vector_type(4))) float floatx4;

#define THSTEP 0.00038349519697141023f  /* (pi/2)/4096 */

__device__ inline float bf16_to_f(unsigned short u) {
    return __uint_as_float(((unsigned)u) << 16);
}
__device__ inline unsigned short f_to_bf16(float f) {
    unsigned u = __float_as_uint(f);
    unsigned r = (u + 0x7FFFu + ((u >> 16) & 1u)) >> 16;  // RNE
    return (unsigned short)r;
}

// async global->LDS DMA, 16B per lane, wave-uniform LDS base + lane*16 dest.
// Source addresses are pre-swizzled (chunk c ^ (r&7)); LDS dest is linear —
// the G21 "inverse-swz source + linear dest + swz read" pattern.
__device__ inline void gl_lds16(const void* g, void* l) {
    __builtin_amdgcn_global_load_lds(
        (const __attribute__((address_space(1))) void*)g,
        (__attribute__((address_space(3))) void*)l, 16, 0, 0);
}

// ---------------------------------------------------------------------------
// Split pass 1: x (fp32) -> xh (bf16 round)
// ---------------------------------------------------------------------------
__global__ __launch_bounds__(256) void split_x_kernel(
    const float* __restrict__ x, ushort* __restrict__ xh)
{
    int i = blockIdx.x * 256 + threadIdx.x;          // over float4s, exact grid
    float4 v = ((const float4*)x)[i];
    ushort4 hh;
    hh.x = f_to_bf16(v.x); hh.y = f_to_bf16(v.y);
    hh.z = f_to_bf16(v.z); hh.w = f_to_bf16(v.w);
    ((ushort4*)xh)[i] = hh;
}

// Split pass 2: Wq,Wk -> hi+lo bf16; Wv -> hi only
__global__ __launch_bounds__(256) void split_w_kernel(
    const float* __restrict__ Wq, const float* __restrict__ Wk,
    const float* __restrict__ Wv,
    ushort* __restrict__ Wqh, ushort* __restrict__ Wql,
    ushort* __restrict__ Wkh, ushort* __restrict__ Wkl,
    ushort* __restrict__ Wvh)
{
    int i = blockIdx.x * 256 + threadIdx.x;          // over float4s, exact grid
    float4 q = ((const float4*)Wq)[i];
    float4 k = ((const float4*)Wk)[i];
    float4 v = ((const float4*)Wv)[i];
    ushort4 h, l;
    h.x=f_to_bf16(q.x); l.x=f_to_bf16(q.x-bf16_to_f(h.x));
    h.y=f_to_bf16(q.y); l.y=f_to_bf16(q.y-bf16_to_f(h.y));
    h.z=f_to_bf16(q.z); l.z=f_to_bf16(q.z-bf16_to_f(h.z));
    h.w=f_to_bf16(q.w); l.w=f_to_bf16(q.w-bf16_to_f(h.w));
    ((ushort4*)Wqh)[i]=h; ((ushort4*)Wql)[i]=l;
    h.x=f_to_bf16(k.x); l.x=f_to_bf16(k.x-bf16_to_f(h.x));
    h.y=f_to_bf16(k.y); l.y=f_to_bf16(k.y-bf16_to_f(h.y));
    h.z=f_to_bf16(k.z); l.z=f_to_bf16(k.z-bf16_to_f(h.z));
    h.w=f_to_bf16(k.w); l.w=f_to_bf16(k.w-bf16_to_f(h.w));
    ((ushort4*)Wkh)[i]=h; ((ushort4*)Wkl)[i]=l;
    h.x=f_to_bf16(v.x); h.y=f_to_bf16(v.y);
    h.z=f_to_bf16(v.z); h.w=f_to_bf16(v.w);
    ((ushort4*)Wvh)[i]=h;
}

// ---------------------------------------------------------------------------
// Kernel 1: QKV GEMM, pure bf16.  SINGLE A-pass: per K-step stage A, Bh, Bl
// and do acc += A*Bh + A*Bl (64 MFMA per barrier-pair).
// R7: staging via global_load_lds (async DMA, no VALU round-trip / ds_write)
//     + grid transposed to dim3(128,8,3) so the 8 blocks sharing an A panel
//     map to the SAME XCD (linear id % 8 == mb % 8) -> A re-reads are L2 hits.
// 128x128 tile, 4 waves, BK=64, XOR-swizzled source chunks, linear LDS dest,
// swizzled ds_read_b128 frags.
// w: 0->q (fp32 out), 1->k (fp32 out), 2->v (bf16 out, hh only)
// ---------------------------------------------------------------------------
__global__ __launch_bounds__(256) void qkv_gemm(
    const ushort* __restrict__ xh,
    const ushort* __restrict__ Wqh, const ushort* __restrict__ Wql,
    const ushort* __restrict__ Wkh, const ushort* __restrict__ Wkl,
    const ushort* __restrict__ Wvh,
    const float* __restrict__ bq, const float* __restrict__ bk,
    const float* __restrict__ bv,
    float* __restrict__ q32, float* __restrict__ k32, ushort* __restrict__ v16)
{
    __shared__ __align__(16) ushort As[128 * 64];
    __shared__ __align__(16) ushort Bsh[128 * 64];
    __shared__ __align__(16) ushort Bsl[128 * 64];

    const int w = blockIdx.z;
    const ushort* Bhp = (w == 0) ? Wqh : (w == 1) ? Wkh : Wvh;
    const ushort* Blp = (w == 0) ? Wql : Wkl;      // unused when w==2
    const float* bias = (w == 0) ? bq : (w == 1) ? bk : bv;
    const bool lo = (w < 2);

    const int m0 = blockIdx.x * 128;    // m-block on x => id%8 groups A-sharers per XCD
    const int n0 = blockIdx.y * 128;
    const int t = threadIdx.x;
    const int wave = t >> 6, lane = t & 63;
    const int wm = (wave >> 1) * 64, wn = (wave & 1) * 64;
    const int m16 = lane & 15, quad = lane >> 4;

    floatx4 acc[4][4];
#pragma unroll
    for (int i = 0; i < 4; i++)
#pragma unroll
        for (int j = 0; j < 4; j++) acc[i][j] = (floatx4){0.f, 0.f, 0.f, 0.f};

    // per-thread constant staging offsets (32-bit element offsets)
    // slot = i*256 + t; LDS byte dest = slot*16 (linear); source chunk swizzled.
    int aoff[4], boff[4], lbase[4];
#pragma unroll
    for (int i = 0; i < 4; i++) {
        int slot = i * 256 + t;
        int r = slot >> 3, c = slot & 7, g = c ^ (r & 7);
        aoff[i] = (m0 + r) * K_ + g * 8;
        boff[i] = (n0 + r) * K_ + g * 8;
        lbase[i] = (i * 256 + wave * 64) * 8;   // wave-uniform LDS element base
    }

    for (int ks = 0; ks < 16; ++ks) {
        const int kcol = ks * 64;
        // async DMA stage: lane ln of each wave lands at base + ln*16
#pragma unroll
        for (int i = 0; i < 4; i++) {
            gl_lds16(xh + aoff[i] + kcol, &As[lbase[i]]);
            gl_lds16(Bhp + boff[i] + kcol, &Bsh[lbase[i]]);
        }
        if (lo) {
#pragma unroll
            for (int i = 0; i < 4; i++)
                gl_lds16(Blp + boff[i] + kcol, &Bsl[lbase[i]]);
        }
        __syncthreads();   // compiler emits vmcnt(0) drain before s_barrier

#pragma unroll
        for (int kk = 0; kk < 2; ++kk) {
            bf16x8 af[4], bfr[4];
            const int g = kk * 4 + quad;
#pragma unroll
            for (int mt = 0; mt < 4; ++mt) {
                int r = wm + mt * 16 + m16;
                af[mt] = *(const bf16x8*)&As[(r * 8 + (g ^ (r & 7))) * 8];
            }
#pragma unroll
            for (int nt = 0; nt < 4; ++nt) {
                int r2 = wn + nt * 16 + m16;
                bfr[nt] = *(const bf16x8*)&Bsh[(r2 * 8 + (g ^ (r2 & 7))) * 8];
            }
#pragma unroll
            for (int mt = 0; mt < 4; ++mt)
#pragma unroll
                for (int nt = 0; nt < 4; ++nt)
                    acc[mt][nt] = __builtin_amdgcn_mfma_f32_16x16x32_bf16(
                        af[mt], bfr[nt], acc[mt][nt], 0, 0, 0);
            if (lo) {
#pragma unroll
                for (int nt = 0; nt < 4; ++nt) {
                    int r2 = wn + nt * 16 + m16;
                    bfr[nt] = *(const bf16x8*)&Bsl[(r2 * 8 + (g ^ (r2 & 7))) * 8];
                }
#pragma unroll
                for (int mt = 0; mt < 4; ++mt)
#pragma unroll
                    for (int nt = 0; nt < 4; ++nt)
                        acc[mt][nt] = __builtin_amdgcn_mfma_f32_16x16x32_bf16(
                            af[mt], bfr[nt], acc[mt][nt], 0, 0, 0);
            }
        }
        __syncthreads();
    }

    // epilogue:  C row = quad*4+reg, col = lane&15  [m89/m91 verified layout]
    float biasv[4];
#pragma unroll
    for (int nt = 0; nt < 4; nt++)
        biasv[nt] = bias[n0 + wn + nt * 16 + m16];

    if (w < 2) {
        float* dst = (w == 0) ? q32 : k32;
#pragma unroll
        for (int mt = 0; mt < 4; ++mt)
#pragma unroll
            for (int nt = 0; nt < 4; ++nt) {
                int colg = n0 + wn + nt * 16 + m16;
#pragma unroll
                for (int reg = 0; reg < 4; ++reg) {
                    int rowg = m0 + wm + mt * 16 + quad * 4 + reg;
                    dst[(size_t)rowg * E_ + colg] = acc[mt][nt][reg] + biasv[nt];
                }
            }
    } else {
#pragma unroll
        for (int mt = 0; mt < 4; ++mt)
#pragma unroll
            for (int nt = 0; nt < 4; ++nt) {
                int colg = n0 + wn + nt * 16 + m16;
#pragma unroll
                for (int reg = 0; reg < 4; ++reg) {
                    int rowg = m0 + wm + mt * 16 + quad * 4 + reg;
                    v16[(size_t)rowg * E_ + colg] = f_to_bf16(acc[mt][nt][reg] + biasv[nt]);
                }
            }
    }
}

// ---------------------------------------------------------------------------
// Kernel 2: approx scores[b,h,s] = sum_d q*k (raw q,k fp32). one wave/token
// ---------------------------------------------------------------------------
__global__ __launch_bounds__(256) void scores_kernel(
    const float* __restrict__ q32, const float* __restrict__ k32,
    float* __restrict__ scores)
{
    int wid = blockIdx.x * 4 + (threadIdx.x >> 6);
    int lane = threadIdx.x & 63;
    int s = wid & (S_ - 1);
    int bh = wid >> 12;
    int b = bh >> 4, h = bh & 15;
    size_t addr = (size_t)(b * S_ + s) * E_ + h * 64 + lane;
    float p = q32[addr] * k32[addr];
#pragma unroll
    for (int m = 32; m; m >>= 1) p += __shfl_xor(p, m, 64);
    if (lane == 0) scores[wid] = p;
}

// ---------------------------------------------------------------------------
// Kernel 3: radix-select 1024th approx score T_a; classify into definite-in
// (> T_a+DELTA) and band (|score-T_a| <= DELTA).  Bucket pick via parallel
// suffix-scan.
// ---------------------------------------------------------------------------
__global__ __launch_bounds__(256) void band_select_kernel(
    const float* __restrict__ scores, int* __restrict__ selidx,
    int* __restrict__ band, int* __restrict__ meta)
{
    __shared__ unsigned keys[4096];
    __shared__ unsigned hist[256];
    __shared__ unsigned suf[256];
    __shared__ unsigned bcast[2];
    __shared__ int cnt_in, cnt_band;

    int bh = blockIdx.x;
    int t = threadIdx.x;
    const float* sc = scores + (size_t)bh * S_;

    for (int i = t; i < 4096; i += 256) {
        unsigned u = __float_as_uint(sc[i]);
        u = (u & 0x80000000u) ? ~u : (u | 0x80000000u);
        keys[i] = u;
    }
    if (t == 0) { cnt_in = 0; cnt_band = 0; }
    __syncthreads();

    unsigned prefix = 0, want = NS_;
    for (int shift = 24; shift >= 0; shift -= 8) {
        hist[t] = 0;
        __syncthreads();
        unsigned pmask = (shift == 24) ? 0u : (0xFFFFFFFFu << (shift + 8));
        for (int i = t; i < 4096; i += 256) {
            unsigned ky = keys[i];
            if ((ky & pmask) == prefix) atomicAdd(&hist[(ky >> shift) & 255u], 1u);
        }
        __syncthreads();
        // suffix sum: suf[t] = sum_{b>=t} hist[b]  (Hillis-Steele, 8 steps)
        suf[t] = hist[t];
        __syncthreads();
        for (int off = 1; off < 256; off <<= 1) {
            unsigned add = (t + off < 256) ? suf[t + off] : 0u;
            __syncthreads();
            suf[t] += add;
            __syncthreads();
        }
        unsigned Sb = suf[t];
        unsigned Snx = (t < 255) ? suf[t + 1] : 0u;
        if (Sb >= want && Snx < want) {          // unique t: S is decreasing
            bcast[0] = (unsigned)t;
            bcast[1] = want - Snx;
        }
        __syncthreads();
        prefix = prefix | (bcast[0] << shift);
        want = bcast[1];
        __syncthreads();
    }
    unsigned fb = (prefix & 0x80000000u) ? (prefix ^ 0x80000000u) : ~prefix;
    float Ta = __uint_as_float(fb);
    float Thi = Ta + DELTA, Tlo = Ta - DELTA;

    int* sel = selidx + (size_t)bh * NS_;
    int* bnd = band + (size_t)bh * BANDCAP;
    for (int i = t; i < 4096; i += 256) {
        float v = sc[i];
        if (v > Thi) {
            int p = atomicAdd(&cnt_in, 1);
            sel[p] = i;
        } else if (v >= Tlo) {
            int p = atomicAdd(&cnt_band, 1);
            if (p < BANDCAP) bnd[p] = i;
        }
    }
    __syncthreads();
    if (t == 0) {
        meta[bh * 2 + 0] = cnt_in;
        meta[bh * 2 + 1] = (cnt_band < BANDCAP) ? cnt_band : BANDCAP;
    }
}

// ---------------------------------------------------------------------------
// Kernel 4: exact fp64 band rescoring — one block per band token, 512 thr
// (8 waves x 16 rows).  Coalesced: lane l reads float4 #(l+64p) of the W row.
// ---------------------------------------------------------------------------
__global__ __launch_bounds__(512) void band_exact_kernel(
    const float* __restrict__ x,
    const float* __restrict__ Wq, const float* __restrict__ Wk,
    const int* __restrict__ band, const int* __restrict__ meta,
    double* __restrict__ bscore)
{
    int j = blockIdx.x, bh = blockIdx.y;
    int NB = meta[bh * 2 + 1];
    if (j >= NB) return;
    int b = bh >> 4, h = bh & 15;
    int s = band[(size_t)bh * BANDCAP + j];
    int t = threadIdx.x;
    int wave = t >> 6, lane = t & 63;

    __shared__ float xs[1024];
    __shared__ double qkd[128];     // [0:64)=q dots, [64:128)=k dots

    if (t < 256)
        *(float4*)&xs[t * 4] = *(const float4*)(x + (size_t)(b * S_ + s) * K_ + t * 4);
    __syncthreads();

    // waves 0-3: Wq rows 16*wave.. | waves 4-7: Wk rows 16*(wave-4)..
    const float* Wbase = (wave < 4) ? Wq : Wk;
    int role = wave >> 2;
    int dbase = (wave & 3) * 16;
    const float4* xs4 = (const float4*)xs;

    for (int rr = 0; rr < 16; ++rr) {
        int d = dbase + rr;
        const float4* wrow4 = (const float4*)(Wbase + (size_t)(h * 64 + d) * K_);
        double a = 0.0;
#pragma unroll
        for (int p = 0; p < 4; ++p) {
            float4 wv = wrow4[lane + 64 * p];
            float4 xv = xs4[lane + 64 * p];
            a += (double)xv.x * wv.x + (double)xv.y * wv.y
               + (double)xv.z * wv.z + (double)xv.w * wv.w;
        }
#pragma unroll
        for (int m = 32; m; m >>= 1) a += __shfl_xor(a, m, 64);
        if (lane == 0) qkd[role * 64 + d] = a;
    }
    __syncthreads();

    if (t < 64) {
        double p = qkd[t] * qkd[64 + t];
#pragma unroll
        for (int m = 32; m; m >>= 1) p += __shfl_xor(p, m, 64);
        if (t == 0) bscore[(size_t)bh * BANDCAP + j] = p;
    }
}

// Kernel 5: rank band tokens (ties -> lower index), fill selidx positions.
__global__ __launch_bounds__(128) void band_rank_kernel(
    const double* __restrict__ bscore, const int* __restrict__ band,
    const int* __restrict__ meta, int* __restrict__ selidx)
{
    __shared__ double sc[BANDCAP];
    __shared__ int bi[BANDCAP];
    int bh = blockIdx.x, t = threadIdx.x;
    int cnt_in = meta[bh * 2 + 0], NB = meta[bh * 2 + 1];
    int need = NS_ - cnt_in;
    if (t < NB) {
        sc[t] = bscore[(size_t)bh * BANDCAP + t];
        bi[t] = band[(size_t)bh * BANDCAP + t];
    }
    __syncthreads();
    if (t < NB) {
        double mine = sc[t]; int myi = bi[t]; int r = 0;
        for (int j2 = 0; j2 < NB; ++j2)
            r += (sc[j2] > mine) || (sc[j2] == mine && bi[j2] < myi);
        if (r < need) selidx[(size_t)bh * NS_ + cnt_in + r] = myi;
    }
}

// ---------------------------------------------------------------------------
// Kernel 6: partial KV reductions, LDS-staged coalesced. 16 chunks x 256 toks.
// ---------------------------------------------------------------------------
__global__ __launch_bounds__(256) void kv_partial_kernel(
    const float* __restrict__ k32, const ushort* __restrict__ v16,
    float* __restrict__ kvp)
{
    __shared__ float kls[16 * 64];
    __shared__ float vls[16 * 64];
    int ch = blockIdx.x;   // 0..15
    int bh = blockIdx.y;   // 0..63
    int b = bh >> 4, h = bh & 15;
    int t = threadIdx.x;
    int d0 = (t >> 4) * 4, e0 = (t & 15) * 4;
    int lr = t >> 4, lc = (t & 15) * 4;   // staging map: row, col4

    float accC[4][4] = {}, accS[4][4] = {};
    const float* kbase = k32 + (size_t)b * S_ * E_ + h * 64;
    const ushort* vbase = v16 + (size_t)b * S_ * E_ + h * 64;
    int s0 = ch * 256;

    for (int g = 0; g < 16; ++g) {
        int srow = s0 + g * 16 + lr;
        float4 kf = *(const float4*)(kbase + (size_t)srow * E_ + lc);
        ushort4 vu = *(const ushort4*)(vbase + (size_t)srow * E_ + lc);
        __syncthreads();
        *(float4*)&kls[lr * 64 + lc] = kf;
        float4 vf = { bf16_to_f(vu.x), bf16_to_f(vu.y),
                      bf16_to_f(vu.z), bf16_to_f(vu.w) };
        *(float4*)&vls[lr * 64 + lc] = vf;
        __syncthreads();
#pragma unroll 4
        for (int si = 0; si < 16; ++si) {
            int s = s0 + g * 16 + si;
            float th = (float)s * THSTEP;
            float cw = __cosf(th), sw = __sinf(th);
            float4 kf2 = *(const float4*)&kls[si * 64 + d0];
            float4 vf2 = *(const float4*)&vls[si * 64 + e0];
            float kr[4] = { fmaxf(kf2.x, 0.f), fmaxf(kf2.y, 0.f),
                            fmaxf(kf2.z, 0.f), fmaxf(kf2.w, 0.f) };
            float vv[4] = { vf2.x, vf2.y, vf2.z, vf2.w };
            float kc[4], ksn[4];
#pragma unroll
            for (int i = 0; i < 4; i++) { kc[i] = kr[i] * cw; ksn[i] = kr[i] * sw; }
#pragma unroll
            for (int i = 0; i < 4; i++)
#pragma unroll
                for (int jj = 0; jj < 4; jj++) {
                    accC[i][jj] += kc[i] * vv[jj];
                    accS[i][jj] += ksn[i] * vv[jj];
                }
        }
    }
    float* pc = kvp + ((size_t)(bh * 16 + ch) * 2) * 4096;
    float* ps = pc + 4096;
#pragma unroll
    for (int i = 0; i < 4; i++)
#pragma unroll
        for (int jj = 0; jj < 4; jj++) {
            pc[(d0 + i) * 64 + (e0 + jj)] = accC[i][jj];
            ps[(d0 + i) * 64 + (e0 + jj)] = accS[i][jj];
        }
}

// Kernel 7: reduce the 16 partials -> kv[bh][{cos,sin}][64][64]
__global__ __launch_bounds__(256) void kv_reduce_kernel(
    const float* __restrict__ kvp, float* __restrict__ kv)
{
    int i = blockIdx.x * 256 + threadIdx.x;   // 0 .. 64*2*4096-1
    if (i >= 64 * 2 * 4096) return;
    int bh = i >> 13;
    int rem = i & 8191;
    const float* p = kvp + (size_t)bh * 16 * 8192 + rem;
    float a = 0.f;
#pragma unroll
    for (int c = 0; c < 16; c++) a += p[c * 8192];
    kv[i] = a;
}

// ---------------------------------------------------------------------------
// Kernel 8: sampled = qs_cos @ kv_cos + qs_sin @ kv_sin, scattered to out.
// ---------------------------------------------------------------------------
__global__ __launch_bounds__(256) void sampled_kernel(
    const float* __restrict__ q32, const int* __restrict__ selidx,
    const float* __restrict__ kv, float* __restrict__ out)
{
    __shared__ float kvc[4096];
    __shared__ float kvs[4096];
    __shared__ float qs[256 * 65];
    __shared__ int sidx[256];
    int bh = blockIdx.y;
    int b = bh >> 4, h = bh & 15;
    int t = threadIdx.x;
    int wave = t >> 6, lane = t & 63;

    const float* kvsrc = kv + (size_t)bh * 8192;
    for (int i = t; i < 4096; i += 256) {
        kvc[i] = kvsrc[i];
        kvs[i] = kvsrc[4096 + i];
    }
    sidx[t] = selidx[(size_t)bh * NS_ + blockIdx.x * 256 + t];
    __syncthreads();

    // gather q rows, one row per wave-iteration (coalesced 256B loads)
    for (int i = 0; i < 64; ++i) {
        int row = wave * 64 + i;
        int sr = sidx[row];
        qs[row * 65 + lane] = q32[(size_t)(b * S_ + sr) * E_ + h * 64 + lane];
    }
    __syncthreads();

    int s = sidx[t];
    float th = (float)s * THSTEP;
    float cw = __cosf(th), sw = __sinf(th);

    float acc[64];
#pragma unroll
    for (int e = 0; e < 64; e++) acc[e] = 0.f;

    for (int d = 0; d < 64; ++d) {
        float qd = fmaxf(qs[t * 65 + d], 0.f);
        float a = qd * cw, bb = qd * sw;
        const float4* pc4 = (const float4*)&kvc[d * 64];
        const float4* ps4 = (const float4*)&kvs[d * 64];
#pragma unroll
        for (int e4 = 0; e4 < 16; e4++) {
            float4 c4 = pc4[e4], s4 = ps4[e4];
            acc[e4 * 4 + 0] += a * c4.x + bb * s4.x;
            acc[e4 * 4 + 1] += a * c4.y + bb * s4.y;
            acc[e4 * 4 + 2] += a * c4.z + bb * s4.z;
            acc[e4 * 4 + 3] += a * c4.w + bb * s4.w;
        }
    }
    __syncthreads();
#pragma unroll
    for (int e = 0; e < 64; e++) qs[t * 65 + e] = acc[e];
    __syncthreads();

    // scatter result rows, one row per wave-iteration (coalesced 256B stores)
    for (int i = 0; i < 64; ++i) {
        int row = wave * 64 + i;
        int sr = sidx[row];
        out[(size_t)(b * S_ + sr) * E_ + h * 64 + lane] = qs[row * 65 + lane];
    }
}

__global__ void zero_kernel(uint4* __restrict__ p, int n16)
{
    int stride = gridDim.x * blockDim.x;
    for (int i = blockIdx.x * blockDim.x + threadIdx.x; i < n16; i += stride)
        p[i] = make_uint4(0u, 0u, 0u, 0u);
}

extern "C" void kernel_launch(void* const* d_in, const int* in_sizes, int n_in,
                              void* d_out, int out_size, void* d_ws, size_t ws_size,
                              hipStream_t stream)
{
    const float* x  = (const float*)d_in[0];
    const float* Wq = (const float*)d_in[1];
    const float* bq = (const float*)d_in[2];
    const float* Wk = (const float*)d_in[3];
    const float* bk = (const float*)d_in[4];
    const float* Wv = (const float*)d_in[5];
    const float* bv = (const float*)d_in[6];

    char* ws = (char*)d_ws;
    ushort* xh     = (ushort*)(ws);                   // 33,554,432 B
    float*  kvp    = (float*)(ws);                    // aliases xh (dead after GEMM)
    float*  q32    = (float*)(ws + 33554432);         // 67,108,864 B
    float*  k32    = (float*)(ws + 100663296);        // 67,108,864 B
    ushort* v16    = (ushort*)(ws + 167772160);       // 33,554,432 B
    ushort* Wqh    = (ushort*)(ws + 201326592);       //  2,097,152 B
    ushort* Wql    = (ushort*)(ws + 203423744);
    ushort* Wkh    = (ushort*)(ws + 205520896);
    ushort* Wkl    = (ushort*)(ws + 207618048);
    ushort* Wvh    = (ushort*)(ws + 209715200);
    float*  scores = (float*)(ws + 211812352);        //  1,048,576 B
    int*    selidx = (int*)(ws + 212860928);          //    262,144 B
    int*    band   = (int*)(ws + 213123072);          //     24,576 B
    double* bscore = (double*)(ws + 213147648);       //     49,152 B
    int*    meta   = (int*)(ws + 213196800);          //        512 B
    float*  kv     = (float*)(ws + 213197312);        //  2,097,152 B (end ~205.3 MiB)
    float*  out    = (float*)d_out;

    hipLaunchKernelGGL(zero_kernel, dim3(2048), dim3(256), 0, stream,
                       (uint4*)out, (int)((size_t)M_ * E_ * 4 / 16));
    hipLaunchKernelGGL(split_x_kernel, dim3((M_ * K_) / 1024), dim3(256), 0, stream,
                       x, xh);
    hipLaunchKernelGGL(split_w_kernel, dim3((E_ * E_) / 1024), dim3(256), 0, stream,
                       Wq, Wk, Wv, Wqh, Wql, Wkh, Wkl, Wvh);
    hipLaunchKernelGGL(qkv_gemm, dim3(128, 8, 3), dim3(256), 0, stream,
                       xh, Wqh, Wql, Wkh, Wkl, Wvh, bq, bk, bv, q32, k32, v16);
    hipLaunchKernelGGL(scores_kernel, dim3((B_ * H_ * S_) / 4), dim3(256), 0, stream,
                       q32, k32, scores);
    hipLaunchKernelGGL(band_select_kernel, dim3(B_ * H_), dim3(256), 0, stream,
                       scores, selidx, band, meta);
    hipLaunchKernelGGL(band_exact_kernel, dim3(BANDCAP, B_ * H_), dim3(512), 0, stream,
                       x, Wq, Wk, band, meta, bscore);
    hipLaunchKernelGGL(band_rank_kernel, dim3(B_ * H_), dim3(128), 0, stream,
                       bscore, band, meta, selidx);
    hipLaunchKernelGGL(kv_partial_kernel, dim3(16, 64), dim3(256), 0, stream,
                       k32, v16, kvp);
    hipLaunchKernelGGL(kv_reduce_kernel, dim3(2048), dim3(256), 0, stream,
                       kvp, kv);
    hipLaunchKernelGGL(sampled_kernel, dim3(NS_ / 256, B_ * H_), dim3(256), 0, stream,
                       q32, selidx, kv, out);
}